// Round 9
// baseline (502.898 us; speedup 1.0000x reference)
//
#include <hip/hip_runtime.h>
#include <math.h>

#define NJ 24
#define TPB 256
#define BPT 8             // batches per blend block (sequential inner loop)
#define FK_BPB 8          // batches per FK block

__device__ __constant__ int PAR[NJ] = {-1,0,0,0,1,2,3,4,5,6,7,8,9,9,9,12,13,14,16,17,18,19,20,21};
// Root-first ancestor chain (including self), padded with -1.
__device__ __constant__ int CHAIN[NJ][9] = {
  {0,-1,-1,-1,-1,-1,-1,-1,-1},
  {0, 1,-1,-1,-1,-1,-1,-1,-1},
  {0, 2,-1,-1,-1,-1,-1,-1,-1},
  {0, 3,-1,-1,-1,-1,-1,-1,-1},
  {0, 1, 4,-1,-1,-1,-1,-1,-1},
  {0, 2, 5,-1,-1,-1,-1,-1,-1},
  {0, 3, 6,-1,-1,-1,-1,-1,-1},
  {0, 1, 4, 7,-1,-1,-1,-1,-1},
  {0, 2, 5, 8,-1,-1,-1,-1,-1},
  {0, 3, 6, 9,-1,-1,-1,-1,-1},
  {0, 1, 4, 7,10,-1,-1,-1,-1},
  {0, 2, 5, 8,11,-1,-1,-1,-1},
  {0, 3, 6, 9,12,-1,-1,-1,-1},
  {0, 3, 6, 9,13,-1,-1,-1,-1},
  {0, 3, 6, 9,14,-1,-1,-1,-1},
  {0, 3, 6, 9,12,15,-1,-1,-1},
  {0, 3, 6, 9,13,16,-1,-1,-1},
  {0, 3, 6, 9,14,17,-1,-1,-1},
  {0, 3, 6, 9,13,16,18,-1,-1},
  {0, 3, 6, 9,14,17,19,-1,-1},
  {0, 3, 6, 9,13,16,18,20,-1},
  {0, 3, 6, 9,14,17,19,21,-1},
  {0, 3, 6, 9,13,16,18,20,22},
  {0, 3, 6, 9,14,17,19,21,23},
};

// ---- device helpers ----

__device__ __forceinline__ void fk_local(const float* __restrict__ J_hat,
                                         const float* __restrict__ pose,
                                         int b, int j, float* __restrict__ L /*12*/)
{
  const float rx = pose[b * 72 + j * 3 + 0];
  const float ry = pose[b * 72 + j * 3 + 1];
  const float rz = pose[b * 72 + j * 3 + 2];
  const float theta = sqrtf(rx * rx + ry * ry + rz * rz) + 1e-8f;
  const float inv = 1.0f / theta;
  const float ux = rx * inv, uy = ry * inv, uz = rz * inv;
  const float c = cosf(theta), s = sinf(theta);
  const float ic = 1.0f - c;

  float tx = J_hat[j * 3 + 0];
  float ty = J_hat[j * 3 + 1];
  float tz = J_hat[j * 3 + 2];
  const int p = PAR[j];
  if (p >= 0) {
    tx -= J_hat[p * 3 + 0];
    ty -= J_hat[p * 3 + 1];
    tz -= J_hat[p * 3 + 2];
  }

  L[0]  = c + ic * ux * ux;
  L[1]  = ic * ux * uy - s * uz;
  L[2]  = ic * ux * uz + s * uy;
  L[3]  = tx;
  L[4]  = ic * uy * ux + s * uz;
  L[5]  = c + ic * uy * uy;
  L[6]  = ic * uy * uz - s * ux;
  L[7]  = ty;
  L[8]  = ic * uz * ux - s * uy;
  L[9]  = ic * uz * uy + s * ux;
  L[10] = c + ic * uz * uz;
  L[11] = tz;
}

__device__ __forceinline__ void fk_compose(const float (*__restrict__ Lc)[12],
                                           const float* __restrict__ J_hat,
                                           int j, float* __restrict__ g /*12*/)
{
#pragma unroll
  for (int k = 0; k < 12; k++) g[k] = Lc[0][k];
#pragma unroll
  for (int d = 1; d < 9; d++) {
    const int a = CHAIN[j][d];
    if (a >= 0) {
      float l[12];
#pragma unroll
      for (int k = 0; k < 12; k++) l[k] = Lc[a][k];
      float n[12];
#pragma unroll
      for (int r = 0; r < 3; r++) {
        const float gr0 = g[r * 4 + 0], gr1 = g[r * 4 + 1], gr2 = g[r * 4 + 2];
        n[r * 4 + 0] = gr0 * l[0] + gr1 * l[4] + gr2 * l[8];
        n[r * 4 + 1] = gr0 * l[1] + gr1 * l[5] + gr2 * l[9];
        n[r * 4 + 2] = gr0 * l[2] + gr1 * l[6] + gr2 * l[10];
        n[r * 4 + 3] = gr0 * l[3] + gr1 * l[7] + gr2 * l[11] + g[r * 4 + 3];
      }
#pragma unroll
      for (int k = 0; k < 12; k++) g[k] = n[k];
    }
  }
  // subtract rest-pose joint location: t' = t - R_g @ J_hat[j]
  const float jx = J_hat[j * 3 + 0], jy = J_hat[j * 3 + 1], jz = J_hat[j * 3 + 2];
  g[3]  -= g[0] * jx + g[1] * jy + g[2]  * jz;
  g[7]  -= g[4] * jx + g[5] * jy + g[6]  * jz;
  g[11] -= g[8] * jx + g[9] * jy + g[10] * jz;
}

// ---- kernel 1: forward kinematics, FK_BPB batches per block ----
__global__ __launch_bounds__(FK_BPB * 32) void smpl_fk_kernel(
    const float* __restrict__ J_hat,
    const float* __restrict__ pose,
    float* __restrict__ Gws,   // (B, 24, 12)
    int B)
{
  __shared__ __align__(16) float Lc[FK_BPB][NJ][12];
  const int lb = threadIdx.x >> 5;
  const int j  = threadIdx.x & 31;
  const int b  = blockIdx.x * FK_BPB + lb;
  const bool active = (j < NJ) && (b < B);

  if (active) {
    float L[12];
    fk_local(J_hat, pose, b, j, L);
#pragma unroll
    for (int k = 0; k < 12; k++) Lc[lb][j][k] = L[k];
  }
  __syncthreads();
  if (active) {
    float g[12];
    fk_compose(Lc[lb], J_hat, j, g);
    float* dst = Gws + (size_t)b * (NJ * 12) + j * 12;
#pragma unroll
    for (int k = 0; k < 12; k++) dst[k] = g[k];
  }
}

// ---- kernel 2 (primary): blend, VPT=1, BPT=8, 5-wave VGPR cap ----
// Weights held in registers across the sequential 8-batch loop; G broadcast
// from LDS. launch_bounds(.,5): VGPR <= 102 -> 5 waves/SIMD (live set ~85,
// fits without spilling).
__global__ __launch_bounds__(TPB, 5) void smpl_blend_ws_kernel(
    const float* __restrict__ T_hat,
    const float* __restrict__ weights,
    const float* __restrict__ trans,
    const float* __restrict__ Gws,
    float* __restrict__ out,
    int V)
{
  __shared__ __align__(16) float4 Gs[BPT * NJ * 3];   // 576 float4 = 9.2 KB

  const int b0 = blockIdx.y * BPT;
  const int tid = threadIdx.x;

  // stage 8 batches' G (576 float4) with 256 threads
  {
    const float4* src = reinterpret_cast<const float4*>(Gws + (size_t)b0 * (NJ * 12));
    Gs[tid]           = src[tid];
    Gs[tid + TPB]     = src[tid + TPB];
    if (tid < BPT * NJ * 3 - 2 * TPB) Gs[tid + 2 * TPB] = src[tid + 2 * TPB];
  }
  __syncthreads();

  const int v = blockIdx.x * TPB + tid;
  if (v >= V) return;

  // ---- one-time loads: 24 weights + T_hat xyz (single drain) ----
  float w[24];
  const float4* wp = reinterpret_cast<const float4*>(weights + (size_t)v * 24);
#pragma unroll
  for (int q = 0; q < 6; q++) {
    const float4 t = wp[q];
    w[q * 4 + 0] = t.x; w[q * 4 + 1] = t.y;
    w[q * 4 + 2] = t.z; w[q * 4 + 3] = t.w;
  }
  const float x = T_hat[v * 3 + 0];
  const float y = T_hat[v * 3 + 1];
  const float z = T_hat[v * 3 + 2];

  // ---- sequential batch loop: do NOT unroll (keeps VGPR bounded) ----
#pragma unroll 1
  for (int bi = 0; bi < BPT; bi++) {
    const int b = b0 + bi;
    const float4* __restrict__ Gb = &Gs[bi * NJ * 3];

    float acc[12];
#pragma unroll
    for (int j = 0; j < NJ; j++) {
      const float4 g0 = Gb[j * 3 + 0];
      const float4 g1 = Gb[j * 3 + 1];
      const float4 g2 = Gb[j * 3 + 2];
      const float wj = w[j];
      if (j == 0) {
        acc[0]  = wj * g0.x;  acc[1]  = wj * g0.y;
        acc[2]  = wj * g0.z;  acc[3]  = wj * g0.w;
        acc[4]  = wj * g1.x;  acc[5]  = wj * g1.y;
        acc[6]  = wj * g1.z;  acc[7]  = wj * g1.w;
        acc[8]  = wj * g2.x;  acc[9]  = wj * g2.y;
        acc[10] = wj * g2.z;  acc[11] = wj * g2.w;
      } else {
        acc[0]  = fmaf(wj, g0.x, acc[0]);
        acc[1]  = fmaf(wj, g0.y, acc[1]);
        acc[2]  = fmaf(wj, g0.z, acc[2]);
        acc[3]  = fmaf(wj, g0.w, acc[3]);
        acc[4]  = fmaf(wj, g1.x, acc[4]);
        acc[5]  = fmaf(wj, g1.y, acc[5]);
        acc[6]  = fmaf(wj, g1.z, acc[6]);
        acc[7]  = fmaf(wj, g1.w, acc[7]);
        acc[8]  = fmaf(wj, g2.x, acc[8]);
        acc[9]  = fmaf(wj, g2.y, acc[9]);
        acc[10] = fmaf(wj, g2.z, acc[10]);
        acc[11] = fmaf(wj, g2.w, acc[11]);
      }
    }

    const float t0 = trans[b * 3 + 0];   // block-uniform -> s_load
    const float t1 = trans[b * 3 + 1];
    const float t2 = trans[b * 3 + 2];

    float* op = out + ((size_t)b * V + v) * 3;
    op[0] = acc[0] * x + acc[1] * y + acc[2]  * z + acc[3]  + t0;
    op[1] = acc[4] * x + acc[5] * y + acc[6]  * z + acc[7]  + t1;
    op[2] = acc[8] * x + acc[9] * y + acc[10] * z + acc[11] + t2;
  }
}

// ---- fallback blend (ws too small): FK inline + LDS broadcast, VPT=1 ----
__global__ __launch_bounds__(TPB) void smpl_blend_lds_kernel(
    const float* __restrict__ T_hat,
    const float* __restrict__ J_hat,
    const float* __restrict__ weights,
    const float* __restrict__ pose,
    const float* __restrict__ trans,
    float* __restrict__ out,
    int V)
{
  __shared__ __align__(16) float Lc[NJ][12];
  __shared__ __align__(16) float Gm[NJ][12];
  const int b = blockIdx.y;
  const int tid = threadIdx.x;

  if (tid < NJ) {
    float L[12];
    fk_local(J_hat, pose, b, tid, L);
#pragma unroll
    for (int k = 0; k < 12; k++) Lc[tid][k] = L[k];
  }
  __syncthreads();
  if (tid < NJ) {
    float g[12];
    fk_compose(Lc, J_hat, tid, g);
#pragma unroll
    for (int k = 0; k < 12; k++) Gm[tid][k] = g[k];
  }
  __syncthreads();

  const int v = blockIdx.x * TPB + tid;
  if (v >= V) return;

  float acc[12];
#pragma unroll
  for (int k = 0; k < 12; k++) acc[k] = 0.0f;
  const float* wv = weights + (size_t)v * 24;
#pragma unroll
  for (int j = 0; j < NJ; j++) {
    const float wj = wv[j];
#pragma unroll
    for (int k = 0; k < 12; k++) acc[k] = fmaf(wj, Gm[j][k], acc[k]);
  }
  const float x = T_hat[v * 3 + 0], y = T_hat[v * 3 + 1], z = T_hat[v * 3 + 2];
  float* op = out + ((size_t)b * V + v) * 3;
  op[0] = acc[0] * x + acc[1] * y + acc[2]  * z + acc[3]  + trans[b * 3 + 0];
  op[1] = acc[4] * x + acc[5] * y + acc[6]  * z + acc[7]  + trans[b * 3 + 1];
  op[2] = acc[8] * x + acc[9] * y + acc[10] * z + acc[11] + trans[b * 3 + 2];
}

extern "C" void kernel_launch(void* const* d_in, const int* in_sizes, int n_in,
                              void* d_out, int out_size, void* d_ws, size_t ws_size,
                              hipStream_t stream) {
  const float* T_hat   = (const float*)d_in[0];
  const float* J_hat   = (const float*)d_in[1];
  const float* weights = (const float*)d_in[2];
  const float* pose    = (const float*)d_in[3];
  const float* trans   = (const float*)d_in[4];
  float* out = (float*)d_out;

  const int V = in_sizes[0] / 3;   // 6890
  const int B = in_sizes[3] / 72;  // 512

  const int nvchunks = (V + TPB - 1) / TPB;  // 27

  const size_t ws_needed = (size_t)B * NJ * 12 * sizeof(float);  // 576 KB
  if (ws_size >= ws_needed && (B % BPT) == 0) {
    float* Gws = (float*)d_ws;
    const int fkblocks = (B + FK_BPB - 1) / FK_BPB;  // 64
    smpl_fk_kernel<<<fkblocks, FK_BPB * 32, 0, stream>>>(J_hat, pose, Gws, B);
    dim3 grid(nvchunks, B / BPT);  // (27, 64)
    smpl_blend_ws_kernel<<<grid, TPB, 0, stream>>>(
        T_hat, weights, trans, Gws, out, V);
  } else {
    dim3 grid(nvchunks, B);
    smpl_blend_lds_kernel<<<grid, TPB, 0, stream>>>(
        T_hat, J_hat, weights, pose, trans, out, V);
  }
}

// Round 10
// 34.535 us; speedup vs baseline: 14.5619x; 14.5619x over previous
//
#include <hip/hip_runtime.h>
#include <math.h>

#define NJ 24
#define TPB 256
#define BPT 8             // batches per blend block
#define FK_BPB 8          // batches per FK block

typedef _Float16 f16x8 __attribute__((ext_vector_type(8)));
typedef float f32x4 __attribute__((ext_vector_type(4)));

__device__ __constant__ int PAR[NJ] = {-1,0,0,0,1,2,3,4,5,6,7,8,9,9,9,12,13,14,16,17,18,19,20,21};
__device__ __constant__ int CHAIN[NJ][9] = {
  {0,-1,-1,-1,-1,-1,-1,-1,-1},
  {0, 1,-1,-1,-1,-1,-1,-1,-1},
  {0, 2,-1,-1,-1,-1,-1,-1,-1},
  {0, 3,-1,-1,-1,-1,-1,-1,-1},
  {0, 1, 4,-1,-1,-1,-1,-1,-1},
  {0, 2, 5,-1,-1,-1,-1,-1,-1},
  {0, 3, 6,-1,-1,-1,-1,-1,-1},
  {0, 1, 4, 7,-1,-1,-1,-1,-1},
  {0, 2, 5, 8,-1,-1,-1,-1,-1},
  {0, 3, 6, 9,-1,-1,-1,-1,-1},
  {0, 1, 4, 7,10,-1,-1,-1,-1},
  {0, 2, 5, 8,11,-1,-1,-1,-1},
  {0, 3, 6, 9,12,-1,-1,-1,-1},
  {0, 3, 6, 9,13,-1,-1,-1,-1},
  {0, 3, 6, 9,14,-1,-1,-1,-1},
  {0, 3, 6, 9,12,15,-1,-1,-1},
  {0, 3, 6, 9,13,16,-1,-1,-1},
  {0, 3, 6, 9,14,17,-1,-1,-1},
  {0, 3, 6, 9,13,16,18,-1,-1},
  {0, 3, 6, 9,14,17,19,-1,-1},
  {0, 3, 6, 9,13,16,18,20,-1},
  {0, 3, 6, 9,14,17,19,21,-1},
  {0, 3, 6, 9,13,16,18,20,22},
  {0, 3, 6, 9,14,17,19,21,23},
};

// ---- shared FK helpers ----

__device__ __forceinline__ void fk_local(const float* __restrict__ J_hat,
                                         const float* __restrict__ pose,
                                         int b, int j, float* __restrict__ L /*12*/)
{
  const float rx = pose[b * 72 + j * 3 + 0];
  const float ry = pose[b * 72 + j * 3 + 1];
  const float rz = pose[b * 72 + j * 3 + 2];
  const float theta = sqrtf(rx * rx + ry * ry + rz * rz) + 1e-8f;
  const float inv = 1.0f / theta;
  const float ux = rx * inv, uy = ry * inv, uz = rz * inv;
  const float c = cosf(theta), s = sinf(theta);
  const float ic = 1.0f - c;

  float tx = J_hat[j * 3 + 0];
  float ty = J_hat[j * 3 + 1];
  float tz = J_hat[j * 3 + 2];
  const int p = PAR[j];
  if (p >= 0) {
    tx -= J_hat[p * 3 + 0];
    ty -= J_hat[p * 3 + 1];
    tz -= J_hat[p * 3 + 2];
  }

  L[0]  = c + ic * ux * ux;
  L[1]  = ic * ux * uy - s * uz;
  L[2]  = ic * ux * uz + s * uy;
  L[3]  = tx;
  L[4]  = ic * uy * ux + s * uz;
  L[5]  = c + ic * uy * uy;
  L[6]  = ic * uy * uz - s * ux;
  L[7]  = ty;
  L[8]  = ic * uz * ux - s * uy;
  L[9]  = ic * uz * uy + s * ux;
  L[10] = c + ic * uz * uz;
  L[11] = tz;
}

__device__ __forceinline__ void fk_compose(const float (*__restrict__ Lc)[12],
                                           const float* __restrict__ J_hat,
                                           int j, float* __restrict__ g /*12*/)
{
#pragma unroll
  for (int k = 0; k < 12; k++) g[k] = Lc[0][k];
#pragma unroll
  for (int d = 1; d < 9; d++) {
    const int a = CHAIN[j][d];
    if (a >= 0) {
      float l[12];
#pragma unroll
      for (int k = 0; k < 12; k++) l[k] = Lc[a][k];
      float n[12];
#pragma unroll
      for (int r = 0; r < 3; r++) {
        const float gr0 = g[r * 4 + 0], gr1 = g[r * 4 + 1], gr2 = g[r * 4 + 2];
        n[r * 4 + 0] = gr0 * l[0] + gr1 * l[4] + gr2 * l[8];
        n[r * 4 + 1] = gr0 * l[1] + gr1 * l[5] + gr2 * l[9];
        n[r * 4 + 2] = gr0 * l[2] + gr1 * l[6] + gr2 * l[10];
        n[r * 4 + 3] = gr0 * l[3] + gr1 * l[7] + gr2 * l[11] + g[r * 4 + 3];
      }
#pragma unroll
      for (int k = 0; k < 12; k++) g[k] = n[k];
    }
  }
  const float jx = J_hat[j * 3 + 0], jy = J_hat[j * 3 + 1], jz = J_hat[j * 3 + 2];
  g[3]  -= g[0] * jx + g[1] * jy + g[2]  * jz;
  g[7]  -= g[4] * jx + g[5] * jy + g[6]  * jz;
  g[11] -= g[8] * jx + g[9] * jy + g[10] * jz;
}

// ============================ MFMA path ============================

// prep: weights (V,24) fp32 -> W_h (VP,32) fp16, zero-padded rows & K-tail
__global__ __launch_bounds__(TPB) void smpl_prep_wh(
    const float* __restrict__ weights, _Float16* __restrict__ W_h, int V, int VP)
{
  const int v = blockIdx.x * TPB + threadIdx.x;
  if (v >= VP) return;
  _Float16 row[32];
#pragma unroll
  for (int k = 0; k < 32; k++) row[k] = (_Float16)0.f;
  if (v < V) {
    const float4* wp = reinterpret_cast<const float4*>(weights + (size_t)v * 24);
#pragma unroll
    for (int q = 0; q < 6; q++) {
      const float4 t = wp[q];
      row[q * 4 + 0] = (_Float16)t.x;
      row[q * 4 + 1] = (_Float16)t.y;
      row[q * 4 + 2] = (_Float16)t.z;
      row[q * 4 + 3] = (_Float16)t.w;
    }
  }
  float4* dst = reinterpret_cast<float4*>(W_h + (size_t)v * 32);
  const float4* src = reinterpret_cast<const float4*>(row);
#pragma unroll
  for (int q = 0; q < 4; q++) dst[q] = src[q];
}

// FK -> G_hT (B,16,32) fp16: G_hT[b][c][k=j] = G'_b[j][c], zero-padded
// (cols c>=12 and joints k>=24 are zero).
__global__ __launch_bounds__(FK_BPB * 32) void smpl_fk_gh(
    const float* __restrict__ J_hat,
    const float* __restrict__ pose,
    _Float16* __restrict__ G_hT,
    int B)
{
  __shared__ __align__(16) float Lc[FK_BPB][NJ][12];
  const int lb = threadIdx.x >> 5;
  const int j  = threadIdx.x & 31;
  const int b  = blockIdx.x * FK_BPB + lb;
  const bool compute = (j < NJ) && (b < B);

  if (compute) {
    float L[12];
    fk_local(J_hat, pose, b, j, L);
#pragma unroll
    for (int k = 0; k < 12; k++) Lc[lb][j][k] = L[k];
  }
  __syncthreads();

  float g[12];
#pragma unroll
  for (int k = 0; k < 12; k++) g[k] = 0.0f;
  if (compute) fk_compose(Lc[lb], J_hat, j, g);

  if (b < B) {
    _Float16* dst = G_hT + (size_t)b * 512;   // [16][32]
#pragma unroll
    for (int c = 0; c < 16; c++) {
      _Float16 val = (_Float16)0.f;
      if (j < NJ && c < 12) val = (_Float16)g[c];
      dst[c * 32 + j] = val;   // lanes j contiguous -> coalesced u16
    }
  }
}

// blend: per wave 64 vertices x 8 batches via mfma_f32_16x16x32_f16.
// A: row=lane&15, k=(lane>>4)*8+e (W_h rows). B: col=lane&15, same k (G_hT).
// C/D: col=lane&15, row=(lane>>4)*4+reg  [m89-verified family mapping].
__global__ __launch_bounds__(TPB) void smpl_blend_mfma(
    const float* __restrict__ T_hat,
    const _Float16* __restrict__ W_h,
    const float* __restrict__ trans,
    const _Float16* __restrict__ G_hT,
    float* __restrict__ out,
    int V)
{
  // per-wave C-transpose buffer: [16 cols][72 rows-padded] fp32
  __shared__ __align__(16) float Cbuf[4][16 * 72];   // 18432 B

  const int tid  = threadIdx.x;
  const int wid  = tid >> 6;
  const int lane = tid & 63;
  const int vbase = blockIdx.x * 256 + wid * 64;
  const int b0 = blockIdx.y * BPT;

  const int fr = lane & 15;   // A-row / B-col / C-col
  const int kb = lane >> 4;   // k-block

  // A fragments (4 m-tiles), held across all batches
  f16x8 afrag[4];
#pragma unroll
  for (int t = 0; t < 4; t++)
    afrag[t] = *reinterpret_cast<const f16x8*>(
        W_h + ((size_t)(vbase + t * 16 + fr)) * 32 + kb * 8);

  // B fragments for all 8 batches (one vmcnt drain)
  f16x8 bfrag[BPT];
#pragma unroll
  for (int bi = 0; bi < BPT; bi++)
    bfrag[bi] = *reinterpret_cast<const f16x8*>(
        G_hT + ((size_t)(b0 + bi) * 16 + fr) * 32 + kb * 8);

  const int myv = vbase + lane;   // vertex this lane owns in the epilogue
  float x = 0.f, y = 0.f, z = 0.f;
  if (myv < V) {
    x = T_hat[myv * 3 + 0];
    y = T_hat[myv * 3 + 1];
    z = T_hat[myv * 3 + 2];
  }

  float* __restrict__ cb = &Cbuf[wid][0];
  const int wrow = (lane >> 4) * 4;   // C row base for this lane

#pragma unroll
  for (int bi = 0; bi < BPT; bi++) {
    const int b = b0 + bi;

    // 4 MFMA tiles -> LDS (col-major with pad 72; write b128, 4-way max)
#pragma unroll
    for (int t = 0; t < 4; t++) {
      f32x4 acc = {0.f, 0.f, 0.f, 0.f};
      acc = __builtin_amdgcn_mfma_f32_16x16x32_f16(afrag[t], bfrag[bi], acc, 0, 0, 0);
      *reinterpret_cast<f32x4*>(cb + fr * 72 + t * 16 + wrow) = acc;
    }

    // transpose read: lane reads its vertex's 12 blended-transform values
    float c[12];
#pragma unroll
    for (int q = 0; q < 12; q++) c[q] = cb[q * 72 + lane];

    if (myv < V) {
      const float t0 = trans[b * 3 + 0];   // block-uniform -> s_load
      const float t1 = trans[b * 3 + 1];
      const float t2 = trans[b * 3 + 2];
      float* op = out + ((size_t)b * V + myv) * 3;
      op[0] = c[0] * x + c[1] * y + c[2]  * z + c[3]  + t0;
      op[1] = c[4] * x + c[5] * y + c[6]  * z + c[7]  + t1;
      op[2] = c[8] * x + c[9] * y + c[10] * z + c[11] + t2;
    }
  }
}

// ======================= fallback path (round-8, proven 58 us) =======================

__global__ __launch_bounds__(FK_BPB * 32) void smpl_fk_kernel(
    const float* __restrict__ J_hat,
    const float* __restrict__ pose,
    float* __restrict__ Gws, int B)
{
  __shared__ __align__(16) float Lc[FK_BPB][NJ][12];
  const int lb = threadIdx.x >> 5;
  const int j  = threadIdx.x & 31;
  const int b  = blockIdx.x * FK_BPB + lb;
  const bool active = (j < NJ) && (b < B);

  if (active) {
    float L[12];
    fk_local(J_hat, pose, b, j, L);
#pragma unroll
    for (int k = 0; k < 12; k++) Lc[lb][j][k] = L[k];
  }
  __syncthreads();
  if (active) {
    float g[12];
    fk_compose(Lc[lb], J_hat, j, g);
    float* dst = Gws + (size_t)b * (NJ * 12) + j * 12;
#pragma unroll
    for (int k = 0; k < 12; k++) dst[k] = g[k];
  }
}

__global__ __launch_bounds__(TPB) void smpl_blend_ws_kernel(
    const float* __restrict__ T_hat,
    const float* __restrict__ weights,
    const float* __restrict__ trans,
    const float* __restrict__ Gws,
    float* __restrict__ out, int V)
{
  __shared__ __align__(16) float4 Gs[4 * NJ * 3];

  const int b0 = blockIdx.y * 4;
  const int tid = threadIdx.x;
  {
    const float4* src = reinterpret_cast<const float4*>(Gws + (size_t)b0 * (NJ * 12));
    Gs[tid] = src[tid];
    if (tid < 4 * NJ * 3 - TPB) Gs[TPB + tid] = src[TPB + tid];
  }
  __syncthreads();

  const int v = blockIdx.x * TPB + tid;
  if (v >= V) return;

  float w[24];
  const float4* wp = reinterpret_cast<const float4*>(weights + (size_t)v * 24);
#pragma unroll
  for (int q = 0; q < 6; q++) {
    const float4 t = wp[q];
    w[q * 4 + 0] = t.x; w[q * 4 + 1] = t.y;
    w[q * 4 + 2] = t.z; w[q * 4 + 3] = t.w;
  }
  const float x = T_hat[v * 3 + 0];
  const float y = T_hat[v * 3 + 1];
  const float z = T_hat[v * 3 + 2];

#pragma unroll 1
  for (int bi = 0; bi < 4; bi++) {
    const int b = b0 + bi;
    const float4* __restrict__ Gb = &Gs[bi * NJ * 3];
    float acc[12];
#pragma unroll
    for (int j = 0; j < NJ; j++) {
      const float4 g0 = Gb[j * 3 + 0];
      const float4 g1 = Gb[j * 3 + 1];
      const float4 g2 = Gb[j * 3 + 2];
      const float wj = w[j];
      if (j == 0) {
        acc[0]  = wj * g0.x;  acc[1]  = wj * g0.y;
        acc[2]  = wj * g0.z;  acc[3]  = wj * g0.w;
        acc[4]  = wj * g1.x;  acc[5]  = wj * g1.y;
        acc[6]  = wj * g1.z;  acc[7]  = wj * g1.w;
        acc[8]  = wj * g2.x;  acc[9]  = wj * g2.y;
        acc[10] = wj * g2.z;  acc[11] = wj * g2.w;
      } else {
        acc[0]  = fmaf(wj, g0.x, acc[0]);
        acc[1]  = fmaf(wj, g0.y, acc[1]);
        acc[2]  = fmaf(wj, g0.z, acc[2]);
        acc[3]  = fmaf(wj, g0.w, acc[3]);
        acc[4]  = fmaf(wj, g1.x, acc[4]);
        acc[5]  = fmaf(wj, g1.y, acc[5]);
        acc[6]  = fmaf(wj, g1.z, acc[6]);
        acc[7]  = fmaf(wj, g1.w, acc[7]);
        acc[8]  = fmaf(wj, g2.x, acc[8]);
        acc[9]  = fmaf(wj, g2.y, acc[9]);
        acc[10] = fmaf(wj, g2.z, acc[10]);
        acc[11] = fmaf(wj, g2.w, acc[11]);
      }
    }
    const float t0 = trans[b * 3 + 0];
    const float t1 = trans[b * 3 + 1];
    const float t2 = trans[b * 3 + 2];
    float* op = out + ((size_t)b * V + v) * 3;
    op[0] = acc[0] * x + acc[1] * y + acc[2]  * z + acc[3]  + t0;
    op[1] = acc[4] * x + acc[5] * y + acc[6]  * z + acc[7]  + t1;
    op[2] = acc[8] * x + acc[9] * y + acc[10] * z + acc[11] + t2;
  }
}

__global__ __launch_bounds__(TPB) void smpl_blend_lds_kernel(
    const float* __restrict__ T_hat,
    const float* __restrict__ J_hat,
    const float* __restrict__ weights,
    const float* __restrict__ pose,
    const float* __restrict__ trans,
    float* __restrict__ out, int V)
{
  __shared__ __align__(16) float Lc[NJ][12];
  __shared__ __align__(16) float Gm[NJ][12];
  const int b = blockIdx.y;
  const int tid = threadIdx.x;

  if (tid < NJ) {
    float L[12];
    fk_local(J_hat, pose, b, tid, L);
#pragma unroll
    for (int k = 0; k < 12; k++) Lc[tid][k] = L[k];
  }
  __syncthreads();
  if (tid < NJ) {
    float g[12];
    fk_compose(Lc, J_hat, tid, g);
#pragma unroll
    for (int k = 0; k < 12; k++) Gm[tid][k] = g[k];
  }
  __syncthreads();

  const int v = blockIdx.x * TPB + tid;
  if (v >= V) return;

  float acc[12];
#pragma unroll
  for (int k = 0; k < 12; k++) acc[k] = 0.0f;
  const float* wv = weights + (size_t)v * 24;
#pragma unroll
  for (int j = 0; j < NJ; j++) {
    const float wj = wv[j];
#pragma unroll
    for (int k = 0; k < 12; k++) acc[k] = fmaf(wj, Gm[j][k], acc[k]);
  }
  const float x = T_hat[v * 3 + 0], y = T_hat[v * 3 + 1], z = T_hat[v * 3 + 2];
  float* op = out + ((size_t)b * V + v) * 3;
  op[0] = acc[0] * x + acc[1] * y + acc[2]  * z + acc[3]  + trans[b * 3 + 0];
  op[1] = acc[4] * x + acc[5] * y + acc[6]  * z + acc[7]  + trans[b * 3 + 1];
  op[2] = acc[8] * x + acc[9] * y + acc[10] * z + acc[11] + trans[b * 3 + 2];
}

extern "C" void kernel_launch(void* const* d_in, const int* in_sizes, int n_in,
                              void* d_out, int out_size, void* d_ws, size_t ws_size,
                              hipStream_t stream) {
  const float* T_hat   = (const float*)d_in[0];
  const float* J_hat   = (const float*)d_in[1];
  const float* weights = (const float*)d_in[2];
  const float* pose    = (const float*)d_in[3];
  const float* trans   = (const float*)d_in[4];
  float* out = (float*)d_out;

  const int V = in_sizes[0] / 3;   // 6890
  const int B = in_sizes[3] / 72;  // 512

  const int nvchunks = (V + 255) / 256;   // 27
  const int VP = nvchunks * 256;          // 6912

  const size_t wh_bytes = (size_t)VP * 32 * sizeof(_Float16);   // 442368
  const size_t gh_bytes = (size_t)B * 512 * sizeof(_Float16);   // 524288
  const size_t mfma_need = wh_bytes + gh_bytes;                 // ~966 KB
  const size_t ws8_need  = (size_t)B * NJ * 12 * sizeof(float); // 576 KB

  if (ws_size >= mfma_need && (B % BPT) == 0 && (B % FK_BPB) == 0) {
    _Float16* W_h  = (_Float16*)d_ws;
    _Float16* G_hT = (_Float16*)((char*)d_ws + wh_bytes);

    smpl_prep_wh<<<nvchunks, TPB, 0, stream>>>(weights, W_h, V, VP);
    smpl_fk_gh<<<B / FK_BPB, FK_BPB * 32, 0, stream>>>(J_hat, pose, G_hT, B);
    dim3 grid(nvchunks, B / BPT);   // (27, 64)
    smpl_blend_mfma<<<grid, TPB, 0, stream>>>(T_hat, W_h, trans, G_hT, out, V);
  } else if (ws_size >= ws8_need && (B % 4) == 0) {
    float* Gws = (float*)d_ws;
    smpl_fk_kernel<<<(B + FK_BPB - 1) / FK_BPB, FK_BPB * 32, 0, stream>>>(J_hat, pose, Gws, B);
    dim3 grid(nvchunks, B / 4);
    smpl_blend_ws_kernel<<<grid, TPB, 0, stream>>>(T_hat, weights, trans, Gws, out, V);
  } else {
    dim3 grid(nvchunks, B);
    smpl_blend_lds_kernel<<<grid, TPB, 0, stream>>>(T_hat, J_hat, weights, pose, trans, out, V);
  }
}

// Round 11
// 27.750 us; speedup vs baseline: 18.1223x; 1.2445x over previous
//
#include <hip/hip_runtime.h>
#include <math.h>

#define NJ 24
#define TPB 256
#define BPT 8             // batches per blend block
#define FK_BPB 8          // batches per FK block

typedef _Float16 f16x8 __attribute__((ext_vector_type(8)));
typedef float f32x4 __attribute__((ext_vector_type(4)));

__device__ __constant__ int PAR[NJ] = {-1,0,0,0,1,2,3,4,5,6,7,8,9,9,9,12,13,14,16,17,18,19,20,21};
__device__ __constant__ int CHAIN[NJ][9] = {
  {0,-1,-1,-1,-1,-1,-1,-1,-1},
  {0, 1,-1,-1,-1,-1,-1,-1,-1},
  {0, 2,-1,-1,-1,-1,-1,-1,-1},
  {0, 3,-1,-1,-1,-1,-1,-1,-1},
  {0, 1, 4,-1,-1,-1,-1,-1,-1},
  {0, 2, 5,-1,-1,-1,-1,-1,-1},
  {0, 3, 6,-1,-1,-1,-1,-1,-1},
  {0, 1, 4, 7,-1,-1,-1,-1,-1},
  {0, 2, 5, 8,-1,-1,-1,-1,-1},
  {0, 3, 6, 9,-1,-1,-1,-1,-1},
  {0, 1, 4, 7,10,-1,-1,-1,-1},
  {0, 2, 5, 8,11,-1,-1,-1,-1},
  {0, 3, 6, 9,12,-1,-1,-1,-1},
  {0, 3, 6, 9,13,-1,-1,-1,-1},
  {0, 3, 6, 9,14,-1,-1,-1,-1},
  {0, 3, 6, 9,12,15,-1,-1,-1},
  {0, 3, 6, 9,13,16,-1,-1,-1},
  {0, 3, 6, 9,14,17,-1,-1,-1},
  {0, 3, 6, 9,13,16,18,-1,-1},
  {0, 3, 6, 9,14,17,19,-1,-1},
  {0, 3, 6, 9,13,16,18,20,-1},
  {0, 3, 6, 9,14,17,19,21,-1},
  {0, 3, 6, 9,13,16,18,20,22},
  {0, 3, 6, 9,14,17,19,21,23},
};

// ---- shared FK helpers ----

__device__ __forceinline__ void fk_local(const float* __restrict__ J_hat,
                                         const float* __restrict__ pose,
                                         int b, int j, float* __restrict__ L /*12*/)
{
  const float rx = pose[b * 72 + j * 3 + 0];
  const float ry = pose[b * 72 + j * 3 + 1];
  const float rz = pose[b * 72 + j * 3 + 2];
  const float theta = sqrtf(rx * rx + ry * ry + rz * rz) + 1e-8f;
  const float inv = 1.0f / theta;
  const float ux = rx * inv, uy = ry * inv, uz = rz * inv;
  const float c = cosf(theta), s = sinf(theta);
  const float ic = 1.0f - c;

  float tx = J_hat[j * 3 + 0];
  float ty = J_hat[j * 3 + 1];
  float tz = J_hat[j * 3 + 2];
  const int p = PAR[j];
  if (p >= 0) {
    tx -= J_hat[p * 3 + 0];
    ty -= J_hat[p * 3 + 1];
    tz -= J_hat[p * 3 + 2];
  }

  L[0]  = c + ic * ux * ux;
  L[1]  = ic * ux * uy - s * uz;
  L[2]  = ic * ux * uz + s * uy;
  L[3]  = tx;
  L[4]  = ic * uy * ux + s * uz;
  L[5]  = c + ic * uy * uy;
  L[6]  = ic * uy * uz - s * ux;
  L[7]  = ty;
  L[8]  = ic * uz * ux - s * uy;
  L[9]  = ic * uz * uy + s * ux;
  L[10] = c + ic * uz * uz;
  L[11] = tz;
}

__device__ __forceinline__ void fk_compose(const float (*__restrict__ Lc)[12],
                                           const float* __restrict__ J_hat,
                                           int j, float* __restrict__ g /*12*/)
{
#pragma unroll
  for (int k = 0; k < 12; k++) g[k] = Lc[0][k];
#pragma unroll
  for (int d = 1; d < 9; d++) {
    const int a = CHAIN[j][d];
    if (a >= 0) {
      float l[12];
#pragma unroll
      for (int k = 0; k < 12; k++) l[k] = Lc[a][k];
      float n[12];
#pragma unroll
      for (int r = 0; r < 3; r++) {
        const float gr0 = g[r * 4 + 0], gr1 = g[r * 4 + 1], gr2 = g[r * 4 + 2];
        n[r * 4 + 0] = gr0 * l[0] + gr1 * l[4] + gr2 * l[8];
        n[r * 4 + 1] = gr0 * l[1] + gr1 * l[5] + gr2 * l[9];
        n[r * 4 + 2] = gr0 * l[2] + gr1 * l[6] + gr2 * l[10];
        n[r * 4 + 3] = gr0 * l[3] + gr1 * l[7] + gr2 * l[11] + g[r * 4 + 3];
      }
#pragma unroll
      for (int k = 0; k < 12; k++) g[k] = n[k];
    }
  }
  const float jx = J_hat[j * 3 + 0], jy = J_hat[j * 3 + 1], jz = J_hat[j * 3 + 2];
  g[3]  -= g[0] * jx + g[1] * jy + g[2]  * jz;
  g[7]  -= g[4] * jx + g[5] * jy + g[6]  * jz;
  g[11] -= g[8] * jx + g[9] * jy + g[10] * jz;
}

// ============================ MFMA path ============================

// merged prep: blocks [0, nvchunks) convert weights -> W_h (VP,32) fp16;
// blocks [nvchunks, nvchunks + B/FK_BPB) do FK -> G_hT (B,16,32) fp16.
__global__ __launch_bounds__(TPB) void smpl_prep_all(
    const float* __restrict__ weights,
    const float* __restrict__ J_hat,
    const float* __restrict__ pose,
    _Float16* __restrict__ W_h,
    _Float16* __restrict__ G_hT,
    int V, int VP, int nvchunks, int B)
{
  __shared__ __align__(16) float Lc[FK_BPB][NJ][12];
  const int tid = threadIdx.x;

  if ((int)blockIdx.x < nvchunks) {
    // ---- W_h prep ----
    const int v = blockIdx.x * TPB + tid;
    if (v >= VP) return;
    _Float16 row[32];
#pragma unroll
    for (int k = 0; k < 32; k++) row[k] = (_Float16)0.f;
    if (v < V) {
      const float4* wp = reinterpret_cast<const float4*>(weights + (size_t)v * 24);
#pragma unroll
      for (int q = 0; q < 6; q++) {
        const float4 t = wp[q];
        row[q * 4 + 0] = (_Float16)t.x;
        row[q * 4 + 1] = (_Float16)t.y;
        row[q * 4 + 2] = (_Float16)t.z;
        row[q * 4 + 3] = (_Float16)t.w;
      }
    }
    float4* dst = reinterpret_cast<float4*>(W_h + (size_t)v * 32);
    const float4* src = reinterpret_cast<const float4*>(row);
#pragma unroll
    for (int q = 0; q < 4; q++) dst[q] = src[q];
  } else {
    // ---- FK -> G_hT[b][c12=16][j=32], zero-padded ----
    const int lb = tid >> 5;
    const int j  = tid & 31;
    const int b  = (blockIdx.x - nvchunks) * FK_BPB + lb;
    const bool compute = (j < NJ) && (b < B);

    if (compute) {
      float L[12];
      fk_local(J_hat, pose, b, j, L);
#pragma unroll
      for (int k = 0; k < 12; k++) Lc[lb][j][k] = L[k];
    }
    __syncthreads();

    float g[12];
#pragma unroll
    for (int k = 0; k < 12; k++) g[k] = 0.0f;
    if (compute) fk_compose(Lc[lb], J_hat, j, g);

    if (b < B) {
      _Float16* dst = G_hT + (size_t)b * 512;   // [16][32]
#pragma unroll
      for (int c = 0; c < 16; c++) {
        _Float16 val = (_Float16)0.f;
        if (j < NJ && c < 12) val = (_Float16)g[c];
        dst[c * 32 + j] = val;
      }
    }
  }
}

// blend (no LDS): A = G (rows = c12), B = W (cols = vertices).
// D[row=c12][col=vertex]: lane (fr,kb) holds vertex t*16+fr, c12 rows
// 4kb..4kb+3 in acc[0..3] -> epilogue fully in-register, coalesced stores.
__global__ __launch_bounds__(TPB) void smpl_blend_mfma(
    const float* __restrict__ T_hat,
    const _Float16* __restrict__ W_h,
    const float* __restrict__ trans,
    const _Float16* __restrict__ G_hT,
    float* __restrict__ out,
    int V)
{
  const int tid  = threadIdx.x;
  const int wid  = tid >> 6;
  const int lane = tid & 63;
  const int vbase = blockIdx.x * 256 + wid * 64;
  const int b0 = blockIdx.y * BPT;

  const int fr = lane & 15;   // free index: vertex (B-frag) / c12-row (A-frag)
  const int kb = lane >> 4;   // k-chunk; also this lane's output coordinate

  // W fragments (B-operand): col = vertex vbase + t*16 + fr
  f16x8 wfrag[4];
#pragma unroll
  for (int t = 0; t < 4; t++)
    wfrag[t] = *reinterpret_cast<const f16x8*>(
        W_h + ((size_t)(vbase + t * 16 + fr)) * 32 + kb * 8);

  // G fragments (A-operand): row = c12 = fr, one per batch
  f16x8 gfrag[BPT];
#pragma unroll
  for (int bi = 0; bi < BPT; bi++)
    gfrag[bi] = *reinterpret_cast<const f16x8*>(
        G_hT + ((size_t)(b0 + bi) * 16 + fr) * 32 + kb * 8);

  // T_hat for the 4 vertices this lane finishes (t*16+fr)
  float thx[4], thy[4], thz[4];
#pragma unroll
  for (int t = 0; t < 4; t++) {
    const int v = vbase + t * 16 + fr;
    if (v < V) {
      thx[t] = T_hat[v * 3 + 0];
      thy[t] = T_hat[v * 3 + 1];
      thz[t] = T_hat[v * 3 + 2];
    } else {
      thx[t] = thy[t] = thz[t] = 0.f;
    }
  }

  // trans component for this lane's coordinate (kb), per batch
  const int kc = (kb < 3) ? kb : 2;
  float tsel[BPT];
#pragma unroll
  for (int bi = 0; bi < BPT; bi++) tsel[bi] = trans[(b0 + bi) * 3 + kc];

#pragma unroll
  for (int bi = 0; bi < BPT; bi++) {
    const int b = b0 + bi;
#pragma unroll
    for (int t = 0; t < 4; t++) {
      f32x4 acc = {0.f, 0.f, 0.f, 0.f};
      acc = __builtin_amdgcn_mfma_f32_16x16x32_f16(gfrag[bi], wfrag[t], acc, 0, 0, 0);
      // acc[0..2] = R-row kb of blended transform, acc[3] = translation comp kb
      const float o = acc[0] * thx[t] + acc[1] * thy[t] + acc[2] * thz[t]
                    + acc[3] + tsel[bi];
      const int v = vbase + t * 16 + fr;
      if (kb < 3 && v < V)
        out[((size_t)b * V + v) * 3 + kb] = o;   // 48 lanes cover 192B contig
    }
  }
}

// ======================= fallback path (round-8, proven 58 us) =======================

__global__ __launch_bounds__(FK_BPB * 32) void smpl_fk_kernel(
    const float* __restrict__ J_hat,
    const float* __restrict__ pose,
    float* __restrict__ Gws, int B)
{
  __shared__ __align__(16) float Lc[FK_BPB][NJ][12];
  const int lb = threadIdx.x >> 5;
  const int j  = threadIdx.x & 31;
  const int b  = blockIdx.x * FK_BPB + lb;
  const bool active = (j < NJ) && (b < B);

  if (active) {
    float L[12];
    fk_local(J_hat, pose, b, j, L);
#pragma unroll
    for (int k = 0; k < 12; k++) Lc[lb][j][k] = L[k];
  }
  __syncthreads();
  if (active) {
    float g[12];
    fk_compose(Lc[lb], J_hat, j, g);
    float* dst = Gws + (size_t)b * (NJ * 12) + j * 12;
#pragma unroll
    for (int k = 0; k < 12; k++) dst[k] = g[k];
  }
}

__global__ __launch_bounds__(TPB) void smpl_blend_ws_kernel(
    const float* __restrict__ T_hat,
    const float* __restrict__ weights,
    const float* __restrict__ trans,
    const float* __restrict__ Gws,
    float* __restrict__ out, int V)
{
  __shared__ __align__(16) float4 Gs[4 * NJ * 3];

  const int b0 = blockIdx.y * 4;
  const int tid = threadIdx.x;
  {
    const float4* src = reinterpret_cast<const float4*>(Gws + (size_t)b0 * (NJ * 12));
    Gs[tid] = src[tid];
    if (tid < 4 * NJ * 3 - TPB) Gs[TPB + tid] = src[TPB + tid];
  }
  __syncthreads();

  const int v = blockIdx.x * TPB + tid;
  if (v >= V) return;

  float w[24];
  const float4* wp = reinterpret_cast<const float4*>(weights + (size_t)v * 24);
#pragma unroll
  for (int q = 0; q < 6; q++) {
    const float4 t = wp[q];
    w[q * 4 + 0] = t.x; w[q * 4 + 1] = t.y;
    w[q * 4 + 2] = t.z; w[q * 4 + 3] = t.w;
  }
  const float x = T_hat[v * 3 + 0];
  const float y = T_hat[v * 3 + 1];
  const float z = T_hat[v * 3 + 2];

#pragma unroll 1
  for (int bi = 0; bi < 4; bi++) {
    const int b = b0 + bi;
    const float4* __restrict__ Gb = &Gs[bi * NJ * 3];
    float acc[12];
#pragma unroll
    for (int j = 0; j < NJ; j++) {
      const float4 g0 = Gb[j * 3 + 0];
      const float4 g1 = Gb[j * 3 + 1];
      const float4 g2 = Gb[j * 3 + 2];
      const float wj = w[j];
      if (j == 0) {
        acc[0]  = wj * g0.x;  acc[1]  = wj * g0.y;
        acc[2]  = wj * g0.z;  acc[3]  = wj * g0.w;
        acc[4]  = wj * g1.x;  acc[5]  = wj * g1.y;
        acc[6]  = wj * g1.z;  acc[7]  = wj * g1.w;
        acc[8]  = wj * g2.x;  acc[9]  = wj * g2.y;
        acc[10] = wj * g2.z;  acc[11] = wj * g2.w;
      } else {
        acc[0]  = fmaf(wj, g0.x, acc[0]);
        acc[1]  = fmaf(wj, g0.y, acc[1]);
        acc[2]  = fmaf(wj, g0.z, acc[2]);
        acc[3]  = fmaf(wj, g0.w, acc[3]);
        acc[4]  = fmaf(wj, g1.x, acc[4]);
        acc[5]  = fmaf(wj, g1.y, acc[5]);
        acc[6]  = fmaf(wj, g1.z, acc[6]);
        acc[7]  = fmaf(wj, g1.w, acc[7]);
        acc[8]  = fmaf(wj, g2.x, acc[8]);
        acc[9]  = fmaf(wj, g2.y, acc[9]);
        acc[10] = fmaf(wj, g2.z, acc[10]);
        acc[11] = fmaf(wj, g2.w, acc[11]);
      }
    }
    const float t0 = trans[b * 3 + 0];
    const float t1 = trans[b * 3 + 1];
    const float t2 = trans[b * 3 + 2];
    float* op = out + ((size_t)b * V + v) * 3;
    op[0] = acc[0] * x + acc[1] * y + acc[2]  * z + acc[3]  + t0;
    op[1] = acc[4] * x + acc[5] * y + acc[6]  * z + acc[7]  + t1;
    op[2] = acc[8] * x + acc[9] * y + acc[10] * z + acc[11] + t2;
  }
}

__global__ __launch_bounds__(TPB) void smpl_blend_lds_kernel(
    const float* __restrict__ T_hat,
    const float* __restrict__ J_hat,
    const float* __restrict__ weights,
    const float* __restrict__ pose,
    const float* __restrict__ trans,
    float* __restrict__ out, int V)
{
  __shared__ __align__(16) float Lc[NJ][12];
  __shared__ __align__(16) float Gm[NJ][12];
  const int b = blockIdx.y;
  const int tid = threadIdx.x;

  if (tid < NJ) {
    float L[12];
    fk_local(J_hat, pose, b, tid, L);
#pragma unroll
    for (int k = 0; k < 12; k++) Lc[tid][k] = L[k];
  }
  __syncthreads();
  if (tid < NJ) {
    float g[12];
    fk_compose(Lc, J_hat, tid, g);
#pragma unroll
    for (int k = 0; k < 12; k++) Gm[tid][k] = g[k];
  }
  __syncthreads();

  const int v = blockIdx.x * TPB + tid;
  if (v >= V) return;

  float acc[12];
#pragma unroll
  for (int k = 0; k < 12; k++) acc[k] = 0.0f;
  const float* wv = weights + (size_t)v * 24;
#pragma unroll
  for (int j = 0; j < NJ; j++) {
    const float wj = wv[j];
#pragma unroll
    for (int k = 0; k < 12; k++) acc[k] = fmaf(wj, Gm[j][k], acc[k]);
  }
  const float x = T_hat[v * 3 + 0], y = T_hat[v * 3 + 1], z = T_hat[v * 3 + 2];
  float* op = out + ((size_t)b * V + v) * 3;
  op[0] = acc[0] * x + acc[1] * y + acc[2]  * z + acc[3]  + trans[b * 3 + 0];
  op[1] = acc[4] * x + acc[5] * y + acc[6]  * z + acc[7]  + trans[b * 3 + 1];
  op[2] = acc[8] * x + acc[9] * y + acc[10] * z + acc[11] + trans[b * 3 + 2];
}

extern "C" void kernel_launch(void* const* d_in, const int* in_sizes, int n_in,
                              void* d_out, int out_size, void* d_ws, size_t ws_size,
                              hipStream_t stream) {
  const float* T_hat   = (const float*)d_in[0];
  const float* J_hat   = (const float*)d_in[1];
  const float* weights = (const float*)d_in[2];
  const float* pose    = (const float*)d_in[3];
  const float* trans   = (const float*)d_in[4];
  float* out = (float*)d_out;

  const int V = in_sizes[0] / 3;   // 6890
  const int B = in_sizes[3] / 72;  // 512

  const int nvchunks = (V + 255) / 256;   // 27
  const int VP = nvchunks * 256;          // 6912

  const size_t wh_bytes = (size_t)VP * 32 * sizeof(_Float16);   // 442368
  const size_t gh_bytes = (size_t)B * 512 * sizeof(_Float16);   // 524288
  const size_t mfma_need = wh_bytes + gh_bytes;                 // ~966 KB
  const size_t ws8_need  = (size_t)B * NJ * 12 * sizeof(float); // 576 KB

  if (ws_size >= mfma_need && (B % BPT) == 0 && (B % FK_BPB) == 0) {
    _Float16* W_h  = (_Float16*)d_ws;
    _Float16* G_hT = (_Float16*)((char*)d_ws + wh_bytes);

    const int prep_blocks = nvchunks + B / FK_BPB;   // 27 + 64 = 91
    smpl_prep_all<<<prep_blocks, TPB, 0, stream>>>(
        weights, J_hat, pose, W_h, G_hT, V, VP, nvchunks, B);
    dim3 grid(nvchunks, B / BPT);   // (27, 64)
    smpl_blend_mfma<<<grid, TPB, 0, stream>>>(T_hat, W_h, trans, G_hT, out, V);
  } else if (ws_size >= ws8_need && (B % 4) == 0) {
    float* Gws = (float*)d_ws;
    smpl_fk_kernel<<<(B + FK_BPB - 1) / FK_BPB, FK_BPB * 32, 0, stream>>>(J_hat, pose, Gws, B);
    dim3 grid(nvchunks, B / 4);
    smpl_blend_ws_kernel<<<grid, TPB, 0, stream>>>(T_hat, weights, trans, Gws, out, V);
  } else {
    dim3 grid(nvchunks, B);
    smpl_blend_lds_kernel<<<grid, TPB, 0, stream>>>(T_hat, J_hat, weights, pose, trans, out, V);
  }
}